// Round 12
// baseline (189.674 us; speedup 1.0000x reference)
//
#include <hip/hip_runtime.h>
#include <hip/hip_bf16.h>
#include <math.h>

typedef __bf16 bf16;
typedef __bf16 bf16x8 __attribute__((ext_vector_type(8)));
typedef unsigned short ushort8 __attribute__((ext_vector_type(8)));
typedef float floatx4 __attribute__((ext_vector_type(4)));

#define MFMA_BF16(a, b, c) __builtin_amdgcn_mfma_f32_16x16x32_bf16(a, b, c, 0, 0, 0)

// Q pre-scale: (1/sqrt(64)) * log2(e)  -> scores in log2 domain, p = exp2(s)
#define Q_SCALE 0.18033688011112042f
#define NEG_INVFREQ_LOG2 0.41524101186092029f  // log2(10000)/32
#define INV_2PI 0.15915494309189535f

#if __has_builtin(__builtin_amdgcn_exp2f)
#define EXP2F(x) __builtin_amdgcn_exp2f(x)
#else
#define EXP2F(x) exp2f(x)
#endif

// HW sin/cos: v_sin_f32/v_cos_f32 take REVOLUTIONS; fract to valid domain.
__device__ __forceinline__ void hw_sincos_rev(float rev, float* sn, float* cs) {
#if __has_builtin(__builtin_amdgcn_sinf) && __has_builtin(__builtin_amdgcn_cosf) && \
    __has_builtin(__builtin_amdgcn_fractf)
  const float f = __builtin_amdgcn_fractf(rev);
  *sn = __builtin_amdgcn_sinf(f);
  *cs = __builtin_amdgcn_cosf(f);
#else
  sincosf(rev * 6.2831853071795864f, sn, cs);
#endif
}

__device__ __forceinline__ bf16x8 cvt8(const float4 a, const float4 b) {
  bf16x8 t;
  t[0] = (bf16)a.x; t[1] = (bf16)a.y; t[2] = (bf16)a.z; t[3] = (bf16)a.w;
  t[4] = (bf16)b.x; t[5] = (bf16)b.y; t[6] = (bf16)b.z; t[7] = (bf16)b.w;
  return t;
}

__device__ __forceinline__ unsigned int pack2(float a, float b) {
#if __has_builtin(__builtin_amdgcn_cvt_pk_bf16_f32)
  return __builtin_bit_cast(unsigned int, __builtin_amdgcn_cvt_pk_bf16_f32(a, b));
#else
  unsigned short lo = __builtin_bit_cast(unsigned short, (bf16)a);
  unsigned short hi = __builtin_bit_cast(unsigned short, (bf16)b);
  return (unsigned int)lo | ((unsigned int)hi << 16);
#endif
}

// async global->LDS, 16B/lane; LDS dest = wave-uniform base + lane*16B.
__device__ __forceinline__ void gld16(const bf16* g, bf16* l) {
  __builtin_amdgcn_global_load_lds(
      (const __attribute__((address_space(1))) unsigned int*)g,
      (__attribute__((address_space(3))) unsigned int*)l, 16, 0, 0);
}

// Granule swizzle for [rows][32-bf16] (64B-row) LDS tiles staged by gld16.
// NOTE (r10 measurement): SQ_LDS_BANK_CONFLICT did NOT move with this swizzle
// (counts are structural, from the gld16 DMA-write path), but attn timing
// improved ~2us — kept, zero-cost.
__device__ __forceinline__ int swz_stage_col(int lane) {
  return ((lane & 3) ^ (((lane >> 2) + (lane >> 4)) & 3)) * 8;
}
__device__ __forceinline__ int swz_read_col(int quad, int c) {
  return (quad ^ ((c + (c >> 2)) & 3)) * 8;
}

// XCD-aware block swizzle — ATTN ONLY. Per head, K/V (512 KB) is shared by 16
// blocks; chunked remap gives each XCD 4 complete heads (L2-resident: FETCH
// 64->12 MB measured r8). GEMMs keep DEFAULT mapping (r6: swizzle raised
// FETCH 40->54 MB by replicating B-panels on every XCD).
__device__ __forceinline__ int xcd_swz(int lin, int n) {
  return (lin & 7) * (n >> 3) + (lin >> 3);
}

// ---------------------------------------------------------------------------
// prep: one kernel, 3 jobs (saves 2 graph-node gaps; 3 jobs run concurrently):
//   blocks [0,2048)        : cast x fp32 -> bf16, 8 elems/thread
//   blocks [2048,3584)     : transpose-cast W_qkv [1024][3072] -> [3072][1024]
//   blocks [3584,4096)     : transpose-cast W_out [1024][1024] -> [1024][1024]
// ---------------------------------------------------------------------------
__device__ __forceinline__ void transpose_tile(const float* __restrict__ in,
                                               bf16* __restrict__ out, int N,
                                               int K, int n0, int k0, int t,
                                               bf16 (*T)[40]) {
  {
    const int k = t >> 3, n8 = (t & 7) * 8;
    const float* p = &in[(size_t)(k0 + k) * N + n0 + n8];
    const float4 a = *(const float4*)p;
    const float4 b = *(const float4*)(p + 4);
    const float v[8] = {a.x, a.y, a.z, a.w, b.x, b.y, b.z, b.w};
#pragma unroll
    for (int j = 0; j < 8; j++) {
      const int n = n8 + j;
      T[n][k ^ (8 * ((n >> 3) & 3))] = (bf16)v[j];
    }
  }
  __syncthreads();
  {
    const int n = t >> 2, k8 = (t & 3) * 8;
    const int kp = k8 ^ (8 * ((n >> 3) & 3));
    *(bf16x8*)&out[(size_t)(n0 + n) * K + k0 + k8] = *(const bf16x8*)&T[n][kp];
  }
}

__global__ __launch_bounds__(256) void prep_kernel(
    const float* __restrict__ x, bf16* __restrict__ xb,
    const float* __restrict__ Wqkv, bf16* __restrict__ Wqkvt,
    const float* __restrict__ Wout, bf16* __restrict__ Wot) {
  __shared__ __align__(16) bf16 T[64][40];
  const int b = blockIdx.x, t = threadIdx.x;
  if (b < 2048) {
    const int i = b * 256 + t;
    const float4 a = *(const float4*)&x[(size_t)i * 8];
    const float4 d = *(const float4*)&x[(size_t)i * 8 + 4];
    *(bf16x8*)&xb[(size_t)i * 8] = cvt8(a, d);
  } else if (b < 3584) {
    const int idx = b - 2048;
    transpose_tile(Wqkv, Wqkvt, 3072, 1024, (idx % 48) * 64, (idx / 48) * 32, t,
                   T);
  } else {
    const int idx = b - 3584;
    transpose_tile(Wout, Wot, 1024, 1024, (idx % 16) * 64, (idx / 16) * 32, t,
                   T);
  }
}

// ---------------------------------------------------------------------------
// GEMM: C[M,N] = A[M,K](bf16) @ Bt[N,K](bf16)^T + bias.
// Tile 128 x TN, BK=64, 256 thr. Split-half LDS [2][rows][32], granule-
// swizzled staging/reads (timing-neutral-to-positive; conflicts structural).
// (Round-1 loop structure: 2 barriers/K-step. Pipelining variants measured
//  WORSE: BK=32 dbuf 65us, 3-slot counted-vmcnt 53us vs this 49us. XCD
//  swizzle also WORSE: FETCH 40->54 MB. Default mapping, proven loop.)
// MODE 0: fp32 out. MODE 1 (TN=128): qkv scatter with FUSED RoPE on Q,K.
// V is written TRANSPOSED per head (V^T[bh][d][s]).
// ---------------------------------------------------------------------------
template <int TN, int MODE>
__global__ __launch_bounds__(256) void gemm_kernel(
    const bf16* __restrict__ A, const bf16* __restrict__ Bt,
    const float* __restrict__ bias, void* __restrict__ out0,
    bf16* __restrict__ outK, bf16* __restrict__ outV, int M, int N, int K) {
  constexpr int NI = TN / 32;
  constexpr int BI = TN / 32;
  __shared__ __align__(16) bf16 As2[2][128][32];
  __shared__ __align__(16) bf16 Bs2[2][TN][32];

  const int tid = threadIdx.x, lane = tid & 63, w = tid >> 6;
  const int c = lane & 15, quad = lane >> 4;
  const int wm = w >> 1, wn = w & 1;
  const int m0 = blockIdx.y * 128, n0 = blockIdx.x * TN;
  const int srow = lane >> 2, scol = swz_stage_col(lane);
  const int rcol = swz_read_col(quad, c);

  floatx4 acc[4][NI] = {};

  for (int k0 = 0; k0 < K; k0 += 64) {
    __syncthreads();
#pragma unroll
    for (int i = 0; i < 4; i++) {
      const int seg = w * 4 + i;
      const int kh = seg >> 3, r0 = (seg & 7) * 16;
      gld16(&A[(size_t)(m0 + r0 + srow) * K + k0 + kh * 32 + scol],
            &As2[kh][r0][0]);
    }
#pragma unroll
    for (int i = 0; i < BI; i++) {
      const int seg = w * BI + i;
      const int kh = seg / (TN / 16), r0 = (seg % (TN / 16)) * 16;
      gld16(&Bt[(size_t)(n0 + r0 + srow) * K + k0 + kh * 32 + scol],
            &Bs2[kh][r0][0]);
    }
    __syncthreads();

#pragma unroll
    for (int kh = 0; kh < 2; kh++) {
      bf16x8 af[4], bfr[NI];
#pragma unroll
      for (int mi = 0; mi < 4; mi++)
        af[mi] = *(const bf16x8*)&As2[kh][wm * 64 + mi * 16 + c][rcol];
#pragma unroll
      for (int ni = 0; ni < NI; ni++)
        bfr[ni] = *(const bf16x8*)&Bs2[kh][wn * (TN / 2) + ni * 16 + c][rcol];
#pragma unroll
      for (int mi = 0; mi < 4; mi++)
#pragma unroll
        for (int ni = 0; ni < NI; ni++)
          acc[mi][ni] = MFMA_BF16(af[mi], bfr[ni], acc[mi][ni]);
    }
  }

  if (MODE == 0) {
#pragma unroll
    for (int mi = 0; mi < 4; mi++)
#pragma unroll
      for (int ni = 0; ni < NI; ni++)
#pragma unroll
        for (int r = 0; r < 4; r++) {
          const int row = m0 + wm * 64 + mi * 16 + quad * 4 + r;
          const int col = n0 + wn * (TN / 2) + ni * 16 + c;
          ((float*)out0)[(size_t)row * N + col] = acc[mi][ni][r] + bias[col];
        }
  } else {
    const int colb = n0 + wn * (TN / 2);     // 64-aligned: one (t, head)
    const int t = colb >> 10;                // 0=Q 1=K 2=V
    const int h = (colb & 1023) >> 6;
    bf16* dst = (t == 0) ? (bf16*)out0 : (t == 1 ? outK : outV);
    if (t == 2) {
      // V^T[bh][d][s]: r -> consecutive s -> uint2 (4x bf16) stores.
#pragma unroll
      for (int ni = 0; ni < NI; ni++) {
        const int d = ni * 16 + c;
        const float bv = bias[colb + ni * 16 + c];
#pragma unroll
        for (int mi = 0; mi < 4; mi++) {
          const int row = m0 + wm * 64 + mi * 16 + quad * 4;
          const int b = row >> 11, s = row & 2047;
          const uint2 u = {pack2(acc[mi][ni][0] + bv, acc[mi][ni][1] + bv),
                           pack2(acc[mi][ni][2] + bv, acc[mi][ni][3] + bv)};
          *(uint2*)&dst[(((size_t)b * 16 + h) * 64 + d) * 2048 + s] = u;
        }
      }
    } else {
      const float qs = (t == 0) ? Q_SCALE : 1.0f;
      // inv-freq in REVOLUTIONS per step: 10000^(-d/32) / 2pi
      const float invr[2] = {exp2f(-NEG_INVFREQ_LOG2 * (float)c) * INV_2PI,
                             exp2f(-NEG_INVFREQ_LOG2 * (float)(16 + c)) * INV_2PI};
#pragma unroll
      for (int mi = 0; mi < 4; mi++) {
#pragma unroll
        for (int r = 0; r < 4; r++) {
          const int row = m0 + wm * 64 + mi * 16 + quad * 4 + r;
          const int b = row >> 11, s = row & 2047;
          const size_t base = (((size_t)b * 16 + h) * 2048 + s) * 64;
#pragma unroll
          for (int ni = 0; ni < 2; ni++) {
            float sn, cs;
            hw_sincos_rev((float)s * invr[ni], &sn, &cs);
            const float v1 = acc[mi][ni][r] + bias[colb + ni * 16 + c];
            const float v2 = acc[mi][ni + 2][r] + bias[colb + (ni + 2) * 16 + c];
            const int d = ni * 16 + c;
            dst[base + d] = (bf16)((v1 * cs - v2 * sn) * qs);
            dst[base + d + 32] = (bf16)((v2 * cs + v1 * sn) * qs);
          }
        }
      }
    }
  }
}

// ---------------------------------------------------------------------------
// Causal attention, transposed inner math (S^T/O^T). Scores in log2 domain
// (Q pre-scaled) -> p = exp2(s), single v_exp_f32.
// r12: 512-thread blocks, two 4-wave GROUPS — group 0 computes q-tile qB,
// group 1 computes q-tile qA, in PARALLEL on different waves (was: one wave
// fused both serially). Same grid/LDS/staging volume; per-CU waves 8 -> 16
// (4/SIMD) = 2x latency-hiding for identical total compute. Per-block
// compute stays balanced: (qA+1)+(qB+1) = 33 step-computations for all p.
// Staging spread over all 8 waves (1 K-seg + 1 V-row-group each); group-A
// idle iterations (kt>qA) are block-uniform branches, waves wait at the
// barrier while co-resident blocks use the SIMDs.
// K and V^T staged via async gld16, double-buffered, ONE barrier per kt.
// l (softmax denom) on the MFMA pipe via ones-row PV MFMA. XCD-swizzled
// block mapping (head K/V L2-resident: FETCH 64->12 MB). NO setprio
// (lockstep structure; measured regression r6-r8).
// ---------------------------------------------------------------------------
struct AttnState {
  floatx4 o[4];
  floatx4 l;  // ones-row PV accumulator; all 4 rows equal the denominator
};

__device__ __forceinline__ void attn_step(
    const bf16x8 qf[2], const bf16x8 kf[4][2], const bf16x8 vf[4][2],
    const bf16x8 ones, bf16 (*PsW)[72], AttnState& st, int qglob, int kbase,
    bool diag, int c, int quad) {
  floatx4 sacc[4] = {};
#pragma unroll
  for (int kg = 0; kg < 4; kg++)
#pragma unroll
    for (int dh = 0; dh < 2; dh++)
      sacc[kg] = MFMA_BF16(kf[kg][dh], qf[dh], sacc[kg]);

#pragma unroll
  for (int kg = 0; kg < 4; kg++) {
    float p[4];
#pragma unroll
    for (int r = 0; r < 4; r++) {
      float e = EXP2F(sacc[kg][r]);
      if (diag && (kbase + kg * 16 + quad * 4 + r > qglob)) e = 0.0f;
      p[r] = e;
    }
    const uint2 u = {pack2(p[0], p[1]), pack2(p[2], p[3])};
    *(uint2*)&PsW[c][kg * 16 + quad * 4] = u;
  }

  bf16x8 pf[2];
#pragma unroll
  for (int ks = 0; ks < 2; ks++)
    pf[ks] = *(const bf16x8*)&PsW[c][ks * 32 + quad * 8];

#pragma unroll
  for (int dg = 0; dg < 4; dg++)
#pragma unroll
    for (int ks = 0; ks < 2; ks++)
      st.o[dg] = MFMA_BF16(vf[dg][ks], pf[ks], st.o[dg]);
  st.l = MFMA_BF16(ones, pf[0], st.l);
  st.l = MFMA_BF16(ones, pf[1], st.l);
}

__global__ __launch_bounds__(512) void attn_kernel(const bf16* __restrict__ Q,
                                                   const bf16* __restrict__ K,
                                                   const bf16* __restrict__ V,
                                                   bf16* __restrict__ Aout) {
  const int S = 2048;
  int p, bh;
  {
    const int n = gridDim.x * gridDim.y;  // 512, divisible by 8
    const int swz = xcd_swz(blockIdx.x + gridDim.x * blockIdx.y, n);
    p = swz % gridDim.x;
    bh = swz / gridDim.x;
  }
  const int tid = threadIdx.x, lane = tid & 63, wave = tid >> 6;
  const int c = lane & 15, quad = lane >> 4;
  const int grp = wave >> 2, w4 = wave & 3;

  // [buf][...] double buffers for K and V^T tiles; per-wave P tiles.
  __shared__ __align__(16) bf16 Ks2[2][2][64][32];
  __shared__ __align__(16) bf16 Vt[2][64][64];
  __shared__ __align__(16) bf16 Ps[8][16][72];

  const bf16* Qb = Q + (size_t)bh * S * 64;
  const bf16* Kb = K + (size_t)bh * S * 64;
  const bf16* Vb = V + (size_t)bh * S * 64;  // V^T: [64 d][2048 s]
  const int b = bh >> 4, h = bh & 15;

  const int qA = p, qB = 31 - p;
  const int qtile = (grp == 0) ? qB : qA;    // group 0 -> heavy tile
  const int qg = qtile * 64 + w4 * 16 + c;

  bf16x8 qf[2];
#pragma unroll
  for (int dh = 0; dh < 2; dh++)
    qf[dh] = *(const bf16x8*)&Qb[(size_t)qg * 64 + dh * 32 + quad * 8];

  bf16x8 ones;
#pragma unroll
  for (int j = 0; j < 8; j++) ones[j] = (bf16)1.0f;

  AttnState st = {};

  const int ksr = lane >> 2, ksc = swz_stage_col(lane);
  const int krcol = swz_read_col(quad, c);
  const int vd = lane >> 3;                 // d-row within 8-row group
  const int vg = lane & 7;                  // LDS granule this lane fills

  // stage K tile (1 gld16/wave) + V^T tile (1 gld16/wave), 8 waves cover all
  auto stage = [&](int bb, int kt) {
    const int kt64 = kt * 64;
    {
      const int seg = wave;                  // 8 K-segments of 16 rows
      const int dh = seg >> 2, r0 = (seg & 3) * 16;
      gld16(&Kb[(size_t)(kt64 + r0 + ksr) * 64 + dh * 32 + ksc],
            &Ks2[bb][dh][r0][0]);
    }
    {
      const int d0 = wave * 8;               // 8 V-row-groups of 8 rows
      const int dd = d0 + vd;
      const int g = vg ^ (dd & 7);           // inverse-swizzled global granule
      gld16(&Vb[(size_t)dd * 2048 + kt64 + g * 8], &Vt[bb][d0][0]);
    }
  };

  auto load_kf = [&](int bb, bf16x8 (*kf)[2]) {
#pragma unroll
    for (int kg = 0; kg < 4; kg++)
#pragma unroll
      for (int dh = 0; dh < 2; dh++)
        kf[kg][dh] = *(const bf16x8*)&Ks2[bb][dh][kg * 16 + c][krcol];
  };
  auto load_vf = [&](int bb, bf16x8 (*vf)[2]) {
#pragma unroll
    for (int dg = 0; dg < 4; dg++) {
      const int d = dg * 16 + c;
#pragma unroll
      for (int ks = 0; ks < 2; ks++) {
        const int g = (ks * 4 + quad) ^ (c & 7);  // d&7 == c&7
        vf[dg][ks] = *(const bf16x8*)&Vt[bb][d][g * 8];
      }
    }
  };

  stage(0, 0);
  __syncthreads();

  int buf = 0;
  for (int kt = 0; kt <= qB; kt++) {
    if (kt < qB) stage(buf ^ 1, kt + 1);  // async; loop-end barrier drains
    if (grp == 0 || kt <= qA) {           // block-uniform per group
      bf16x8 kf[4][2], vf[4][2];
      load_kf(buf, kf);
      load_vf(buf, vf);
      attn_step(qf, kf, vf, ones, Ps[wave], st, qg, kt * 64, kt == qtile, c,
                quad);
    }
    __syncthreads();
    buf ^= 1;
  }

  const float iv = 1.0f / st.l[0];
#pragma unroll
  for (int dg = 0; dg < 4; dg++) {
    const uint2 u = {pack2(st.o[dg][0] * iv, st.o[dg][1] * iv),
                     pack2(st.o[dg][2] * iv, st.o[dg][3] * iv)};
    *(uint2*)&Aout[((size_t)b * 2048 + qg) * 1024 + h * 64 + dg * 16 + quad * 4] = u;
  }
}

// ---------------------------------------------------------------------------
extern "C" void kernel_launch(void* const* d_in, const int* in_sizes, int n_in,
                              void* d_out, int out_size, void* d_ws,
                              size_t ws_size, hipStream_t stream) {
  const float* x = (const float*)d_in[0];
  const float* W_qkv = (const float*)d_in[1];
  const float* b_qkv = (const float*)d_in[2];
  const float* W_out = (const float*)d_in[3];
  const float* b_out = (const float*)d_in[4];
  float* out = (float*)d_out;

  const int B = 2, S = 2048, NH = 16;
  const size_t qn = (size_t)B * NH * S * 64;

  bf16* xb = (bf16*)d_ws;
  bf16* Wqkvt = xb + qn;
  bf16* Wot = Wqkvt + 3072 * 1024;
  bf16* Qw = Wot + 1024 * 1024;
  bf16* Kw = Qw + qn;
  bf16* Vw = Kw + qn;   // stored transposed per head: V^T[bh][64 d][2048 s]
  bf16* AO = xb;  // alias: xb dead after gemm_qkv

  prep_kernel<<<dim3(4096), 256, 0, stream>>>(x, xb, W_qkv, Wqkvt, W_out, Wot);

  gemm_kernel<128, 1><<<dim3(3072 / 128, 4096 / 128), 256, 0, stream>>>(
      xb, Wqkvt, b_qkv, Qw, Kw, Vw, 4096, 3072, 1024);
  attn_kernel<<<dim3(16, B * NH), 512, 0, stream>>>(Qw, Kw, Vw, AO);
  gemm_kernel<64, 0><<<dim3(1024 / 64, 4096 / 128), 256, 0, stream>>>(
      AO, Wot, b_out, out, nullptr, nullptr, 4096, 1024, 1024);
}

// Round 13
// 184.710 us; speedup vs baseline: 1.0269x; 1.0269x over previous
//
#include <hip/hip_runtime.h>
#include <hip/hip_bf16.h>
#include <math.h>

typedef __bf16 bf16;
typedef __bf16 bf16x8 __attribute__((ext_vector_type(8)));
typedef unsigned short ushort8 __attribute__((ext_vector_type(8)));
typedef float floatx4 __attribute__((ext_vector_type(4)));

#define MFMA_BF16(a, b, c) __builtin_amdgcn_mfma_f32_16x16x32_bf16(a, b, c, 0, 0, 0)

// Q pre-scale: (1/sqrt(64)) * log2(e)  -> scores in log2 domain, p = exp2(s)
#define Q_SCALE 0.18033688011112042f
#define NEG_INVFREQ_LOG2 0.41524101186092029f  // log2(10000)/32
#define INV_2PI 0.15915494309189535f

#if __has_builtin(__builtin_amdgcn_exp2f)
#define EXP2F(x) __builtin_amdgcn_exp2f(x)
#else
#define EXP2F(x) exp2f(x)
#endif

// HW sin/cos: v_sin_f32/v_cos_f32 take REVOLUTIONS; fract to valid domain.
__device__ __forceinline__ void hw_sincos_rev(float rev, float* sn, float* cs) {
#if __has_builtin(__builtin_amdgcn_sinf) && __has_builtin(__builtin_amdgcn_cosf) && \
    __has_builtin(__builtin_amdgcn_fractf)
  const float f = __builtin_amdgcn_fractf(rev);
  *sn = __builtin_amdgcn_sinf(f);
  *cs = __builtin_amdgcn_cosf(f);
#else
  sincosf(rev * 6.2831853071795864f, sn, cs);
#endif
}

__device__ __forceinline__ bf16x8 cvt8(const float4 a, const float4 b) {
  bf16x8 t;
  t[0] = (bf16)a.x; t[1] = (bf16)a.y; t[2] = (bf16)a.z; t[3] = (bf16)a.w;
  t[4] = (bf16)b.x; t[5] = (bf16)b.y; t[6] = (bf16)b.z; t[7] = (bf16)b.w;
  return t;
}

__device__ __forceinline__ unsigned int pack2(float a, float b) {
#if __has_builtin(__builtin_amdgcn_cvt_pk_bf16_f32)
  return __builtin_bit_cast(unsigned int, __builtin_amdgcn_cvt_pk_bf16_f32(a, b));
#else
  unsigned short lo = __builtin_bit_cast(unsigned short, (bf16)a);
  unsigned short hi = __builtin_bit_cast(unsigned short, (bf16)b);
  return (unsigned int)lo | ((unsigned int)hi << 16);
#endif
}

// async global->LDS, 16B/lane; LDS dest = wave-uniform base + lane*16B.
__device__ __forceinline__ void gld16(const bf16* g, bf16* l) {
  __builtin_amdgcn_global_load_lds(
      (const __attribute__((address_space(1))) unsigned int*)g,
      (__attribute__((address_space(3))) unsigned int*)l, 16, 0, 0);
}

// Granule swizzle for [rows][32-bf16] (64B-row) LDS tiles staged by gld16.
// NOTE (r10 measurement): SQ_LDS_BANK_CONFLICT did NOT move with this swizzle
// (counts are structural, from the gld16 DMA-write path), but attn timing
// improved ~2us — kept, zero-cost.
__device__ __forceinline__ int swz_stage_col(int lane) {
  return ((lane & 3) ^ (((lane >> 2) + (lane >> 4)) & 3)) * 8;
}
__device__ __forceinline__ int swz_read_col(int quad, int c) {
  return (quad ^ ((c + (c >> 2)) & 3)) * 8;
}

// XCD-aware block swizzle — ATTN ONLY. Per head, K/V (512 KB) is shared by 16
// blocks; chunked remap gives each XCD 4 complete heads (L2-resident: FETCH
// 64->12 MB measured r8). GEMMs keep DEFAULT mapping (r6: swizzle raised
// FETCH 40->54 MB by replicating B-panels on every XCD).
__device__ __forceinline__ int xcd_swz(int lin, int n) {
  return (lin & 7) * (n >> 3) + (lin >> 3);
}

// ---------------------------------------------------------------------------
// prep: one kernel, 3 jobs (saves 2 graph-node gaps; 3 jobs run concurrently):
//   blocks [0,2048)        : cast x fp32 -> bf16, 8 elems/thread
//   blocks [2048,3584)     : transpose-cast W_qkv [1024][3072] -> [3072][1024]
//   blocks [3584,4096)     : transpose-cast W_out [1024][1024] -> [1024][1024]
// ---------------------------------------------------------------------------
__device__ __forceinline__ void transpose_tile(const float* __restrict__ in,
                                               bf16* __restrict__ out, int N,
                                               int K, int n0, int k0, int t,
                                               bf16 (*T)[40]) {
  {
    const int k = t >> 3, n8 = (t & 7) * 8;
    const float* p = &in[(size_t)(k0 + k) * N + n0 + n8];
    const float4 a = *(const float4*)p;
    const float4 b = *(const float4*)(p + 4);
    const float v[8] = {a.x, a.y, a.z, a.w, b.x, b.y, b.z, b.w};
#pragma unroll
    for (int j = 0; j < 8; j++) {
      const int n = n8 + j;
      T[n][k ^ (8 * ((n >> 3) & 3))] = (bf16)v[j];
    }
  }
  __syncthreads();
  {
    const int n = t >> 2, k8 = (t & 3) * 8;
    const int kp = k8 ^ (8 * ((n >> 3) & 3));
    *(bf16x8*)&out[(size_t)(n0 + n) * K + k0 + k8] = *(const bf16x8*)&T[n][kp];
  }
}

__global__ __launch_bounds__(256) void prep_kernel(
    const float* __restrict__ x, bf16* __restrict__ xb,
    const float* __restrict__ Wqkv, bf16* __restrict__ Wqkvt,
    const float* __restrict__ Wout, bf16* __restrict__ Wot) {
  __shared__ __align__(16) bf16 T[64][40];
  const int b = blockIdx.x, t = threadIdx.x;
  if (b < 2048) {
    const int i = b * 256 + t;
    const float4 a = *(const float4*)&x[(size_t)i * 8];
    const float4 d = *(const float4*)&x[(size_t)i * 8 + 4];
    *(bf16x8*)&xb[(size_t)i * 8] = cvt8(a, d);
  } else if (b < 3584) {
    const int idx = b - 2048;
    transpose_tile(Wqkv, Wqkvt, 3072, 1024, (idx % 48) * 64, (idx / 48) * 32, t,
                   T);
  } else {
    const int idx = b - 3584;
    transpose_tile(Wout, Wot, 1024, 1024, (idx % 16) * 64, (idx / 16) * 32, t,
                   T);
  }
}

// ---------------------------------------------------------------------------
// GEMM: C[M,N] = A[M,K](bf16) @ Bt[N,K](bf16)^T + bias.
// Tile 128 x TN, templated BK, 256 thr. Split LDS [BK/32][rows][32],
// granule-swizzled staging/reads.
// (Round-1 loop structure: 2 barriers/K-step. Pipelining variants measured
//  WORSE: BK=32 dbuf 65us, 3-slot counted-vmcnt 53us vs this 49us. XCD
//  swizzle also WORSE: FETCH 40->54 MB. Default mapping, proven loop.)
// r13: BK is a template param. Proj (TN=64) runs BK=128 -> 8 K-steps instead
// of 16, halving the per-step barrier-drain count whose cost is fixed; LDS
// 48KB keeps the grid-limited 2 blocks/CU. QKV keeps BK=64 (BK=128 would be
// 64KB LDS -> 3->2 blocks/CU, the m132 regression).
// MODE 0: fp32 out. MODE 1 (TN=128): qkv scatter with FUSED RoPE on Q,K.
// V is written TRANSPOSED per head (V^T[bh][d][s]).
// ---------------------------------------------------------------------------
template <int TN, int MODE, int BK>
__global__ __launch_bounds__(256) void gemm_kernel(
    const bf16* __restrict__ A, const bf16* __restrict__ Bt,
    const float* __restrict__ bias, void* __restrict__ out0,
    bf16* __restrict__ outK, bf16* __restrict__ outV, int M, int N, int K) {
  constexpr int NI = TN / 32;
  constexpr int AL = BK / 16;           // A gld16 per thread per K-step
  constexpr int BL = (TN * BK) / 2048;  // B gld16 per thread per K-step
  __shared__ __align__(16) bf16 As2[BK / 32][128][32];
  __shared__ __align__(16) bf16 Bs2[BK / 32][TN][32];

  const int tid = threadIdx.x, lane = tid & 63, w = tid >> 6;
  const int c = lane & 15, quad = lane >> 4;
  const int wm = w >> 1, wn = w & 1;
  const int m0 = blockIdx.y * 128, n0 = blockIdx.x * TN;
  const int srow = lane >> 2, scol = swz_stage_col(lane);
  const int rcol = swz_read_col(quad, c);

  floatx4 acc[4][NI] = {};

  for (int k0 = 0; k0 < K; k0 += BK) {
    __syncthreads();
#pragma unroll
    for (int i = 0; i < AL; i++) {
      const int seg = w * AL + i;
      const int kh = seg >> 3, r0 = (seg & 7) * 16;
      gld16(&A[(size_t)(m0 + r0 + srow) * K + k0 + kh * 32 + scol],
            &As2[kh][r0][0]);
    }
#pragma unroll
    for (int i = 0; i < BL; i++) {
      const int seg = w * BL + i;
      const int kh = seg / (TN / 16), r0 = (seg % (TN / 16)) * 16;
      gld16(&Bt[(size_t)(n0 + r0 + srow) * K + k0 + kh * 32 + scol],
            &Bs2[kh][r0][0]);
    }
    __syncthreads();

#pragma unroll
    for (int kh = 0; kh < BK / 32; kh++) {
      bf16x8 af[4], bfr[NI];
#pragma unroll
      for (int mi = 0; mi < 4; mi++)
        af[mi] = *(const bf16x8*)&As2[kh][wm * 64 + mi * 16 + c][rcol];
#pragma unroll
      for (int ni = 0; ni < NI; ni++)
        bfr[ni] = *(const bf16x8*)&Bs2[kh][wn * (TN / 2) + ni * 16 + c][rcol];
#pragma unroll
      for (int mi = 0; mi < 4; mi++)
#pragma unroll
        for (int ni = 0; ni < NI; ni++)
          acc[mi][ni] = MFMA_BF16(af[mi], bfr[ni], acc[mi][ni]);
    }
  }

  if (MODE == 0) {
#pragma unroll
    for (int mi = 0; mi < 4; mi++)
#pragma unroll
      for (int ni = 0; ni < NI; ni++)
#pragma unroll
        for (int r = 0; r < 4; r++) {
          const int row = m0 + wm * 64 + mi * 16 + quad * 4 + r;
          const int col = n0 + wn * (TN / 2) + ni * 16 + c;
          ((float*)out0)[(size_t)row * N + col] = acc[mi][ni][r] + bias[col];
        }
  } else {
    const int colb = n0 + wn * (TN / 2);     // 64-aligned: one (t, head)
    const int t = colb >> 10;                // 0=Q 1=K 2=V
    const int h = (colb & 1023) >> 6;
    bf16* dst = (t == 0) ? (bf16*)out0 : (t == 1 ? outK : outV);
    if (t == 2) {
      // V^T[bh][d][s]: r -> consecutive s -> uint2 (4x bf16) stores.
#pragma unroll
      for (int ni = 0; ni < NI; ni++) {
        const int d = ni * 16 + c;
        const float bv = bias[colb + ni * 16 + c];
#pragma unroll
        for (int mi = 0; mi < 4; mi++) {
          const int row = m0 + wm * 64 + mi * 16 + quad * 4;
          const int b = row >> 11, s = row & 2047;
          const uint2 u = {pack2(acc[mi][ni][0] + bv, acc[mi][ni][1] + bv),
                           pack2(acc[mi][ni][2] + bv, acc[mi][ni][3] + bv)};
          *(uint2*)&dst[(((size_t)b * 16 + h) * 64 + d) * 2048 + s] = u;
        }
      }
    } else {
      const float qs = (t == 0) ? Q_SCALE : 1.0f;
      // inv-freq in REVOLUTIONS per step: 10000^(-d/32) / 2pi
      const float invr[2] = {exp2f(-NEG_INVFREQ_LOG2 * (float)c) * INV_2PI,
                             exp2f(-NEG_INVFREQ_LOG2 * (float)(16 + c)) * INV_2PI};
#pragma unroll
      for (int mi = 0; mi < 4; mi++) {
#pragma unroll
        for (int r = 0; r < 4; r++) {
          const int row = m0 + wm * 64 + mi * 16 + quad * 4 + r;
          const int b = row >> 11, s = row & 2047;
          const size_t base = (((size_t)b * 16 + h) * 2048 + s) * 64;
#pragma unroll
          for (int ni = 0; ni < 2; ni++) {
            float sn, cs;
            hw_sincos_rev((float)s * invr[ni], &sn, &cs);
            const float v1 = acc[mi][ni][r] + bias[colb + ni * 16 + c];
            const float v2 = acc[mi][ni + 2][r] + bias[colb + (ni + 2) * 16 + c];
            const int d = ni * 16 + c;
            dst[base + d] = (bf16)((v1 * cs - v2 * sn) * qs);
            dst[base + d + 32] = (bf16)((v2 * cs + v1 * sn) * qs);
          }
        }
      }
    }
  }
}

// ---------------------------------------------------------------------------
// Causal attention, transposed inner math (S^T/O^T). Scores in log2 domain
// (Q pre-scaled) -> p = exp2(s), single v_exp_f32.
// K and V^T staged via async gld16, double-buffered, ONE barrier per kt.
// r11 structure (best measured; r12's 512-thread wave-split was neutral-to-
// worse — TLP is not the limiter): kt-loop PEELED into [0..qA] (both
// q-tiles, FUSED straight-line step) and (qA..qB] (B only).
// l (softmax denom) on the MFMA pipe via ones-row PV MFMA. XCD-swizzled
// block mapping (head K/V L2-resident: FETCH 64->12 MB). NO setprio
// (lockstep structure; measured regression r6-r8).
// ---------------------------------------------------------------------------
struct AttnState {
  floatx4 o[4];
  floatx4 l;  // ones-row PV accumulator; all 4 rows equal the denominator
};

// single-tile step (B-only region; diag at kt==qB)
__device__ __forceinline__ void attn_step(
    const bf16x8 qf[2], const bf16x8 kf[4][2], const bf16x8 vf[4][2],
    const bf16x8 ones, bf16 (*PsW)[72], AttnState& st, int qglob, int kbase,
    bool diag, int c, int quad) {
  floatx4 sacc[4] = {};
#pragma unroll
  for (int kg = 0; kg < 4; kg++)
#pragma unroll
    for (int dh = 0; dh < 2; dh++)
      sacc[kg] = MFMA_BF16(kf[kg][dh], qf[dh], sacc[kg]);

#pragma unroll
  for (int kg = 0; kg < 4; kg++) {
    float p[4];
#pragma unroll
    for (int r = 0; r < 4; r++) {
      float e = EXP2F(sacc[kg][r]);
      if (diag && (kbase + kg * 16 + quad * 4 + r > qglob)) e = 0.0f;
      p[r] = e;
    }
    const uint2 u = {pack2(p[0], p[1]), pack2(p[2], p[3])};
    *(uint2*)&PsW[c][kg * 16 + quad * 4] = u;
  }

  bf16x8 pf[2];
#pragma unroll
  for (int ks = 0; ks < 2; ks++)
    pf[ks] = *(const bf16x8*)&PsW[c][ks * 32 + quad * 8];

#pragma unroll
  for (int dg = 0; dg < 4; dg++)
#pragma unroll
    for (int ks = 0; ks < 2; ks++)
      st.o[dg] = MFMA_BF16(vf[dg][ks], pf[ks], st.o[dg]);
  st.l = MFMA_BF16(ones, pf[0], st.l);
  st.l = MFMA_BF16(ones, pf[1], st.l);
}

// fused two-tile step (kt <= qA): B and A chains interleaved in one
// straight-line block so the scheduler can hide each chain's latency under
// the other's issue. B is never diagonal here (kt <= qA < qB).
__device__ __forceinline__ void attn_step2(
    const bf16x8 qfB[2], const bf16x8 qfA[2], const bf16x8 kf[4][2],
    const bf16x8 vf[4][2], const bf16x8 ones, bf16 (*PsB)[72],
    bf16 (*PsA)[72], AttnState& stB, AttnState& stA, int qgA, int kbase,
    bool diagA, int c, int quad) {
  floatx4 sB[4] = {}, sA[4] = {};
#pragma unroll
  for (int kg = 0; kg < 4; kg++)
#pragma unroll
    for (int dh = 0; dh < 2; dh++) {
      sB[kg] = MFMA_BF16(kf[kg][dh], qfB[dh], sB[kg]);
      sA[kg] = MFMA_BF16(kf[kg][dh], qfA[dh], sA[kg]);
    }

#pragma unroll
  for (int kg = 0; kg < 4; kg++) {
    float pB[4], pA[4];
#pragma unroll
    for (int r = 0; r < 4; r++) {
      pB[r] = EXP2F(sB[kg][r]);
      float e = EXP2F(sA[kg][r]);
      if (diagA && (kbase + kg * 16 + quad * 4 + r > qgA)) e = 0.0f;
      pA[r] = e;
    }
    const uint2 uB = {pack2(pB[0], pB[1]), pack2(pB[2], pB[3])};
    const uint2 uA = {pack2(pA[0], pA[1]), pack2(pA[2], pA[3])};
    *(uint2*)&PsB[c][kg * 16 + quad * 4] = uB;
    *(uint2*)&PsA[c][kg * 16 + quad * 4] = uA;
  }

  bf16x8 pfB[2], pfA[2];
#pragma unroll
  for (int ks = 0; ks < 2; ks++) {
    pfB[ks] = *(const bf16x8*)&PsB[c][ks * 32 + quad * 8];
    pfA[ks] = *(const bf16x8*)&PsA[c][ks * 32 + quad * 8];
  }

#pragma unroll
  for (int dg = 0; dg < 4; dg++)
#pragma unroll
    for (int ks = 0; ks < 2; ks++) {
      stB.o[dg] = MFMA_BF16(vf[dg][ks], pfB[ks], stB.o[dg]);
      stA.o[dg] = MFMA_BF16(vf[dg][ks], pfA[ks], stA.o[dg]);
    }
  stB.l = MFMA_BF16(ones, pfB[0], stB.l);
  stB.l = MFMA_BF16(ones, pfB[1], stB.l);
  stA.l = MFMA_BF16(ones, pfA[0], stA.l);
  stA.l = MFMA_BF16(ones, pfA[1], stA.l);
}

__global__ __launch_bounds__(256) void attn_kernel(const bf16* __restrict__ Q,
                                                   const bf16* __restrict__ K,
                                                   const bf16* __restrict__ V,
                                                   bf16* __restrict__ Aout) {
  const int S = 2048;
  int p, bh;
  {
    const int n = gridDim.x * gridDim.y;  // 512, divisible by 8
    const int swz = xcd_swz(blockIdx.x + gridDim.x * blockIdx.y, n);
    p = swz % gridDim.x;
    bh = swz / gridDim.x;
  }
  const int tid = threadIdx.x, lane = tid & 63, wave = tid >> 6;
  const int c = lane & 15, quad = lane >> 4;

  // [buf][...] double buffers for K and V^T tiles; per-wave/per-step P tiles.
  __shared__ __align__(16) bf16 Ks2[2][2][64][32];
  __shared__ __align__(16) bf16 Vt[2][64][64];
  __shared__ __align__(16) bf16 Ps[4][2][16][72];

  const bf16* Qb = Q + (size_t)bh * S * 64;
  const bf16* Kb = K + (size_t)bh * S * 64;
  const bf16* Vb = V + (size_t)bh * S * 64;  // V^T: [64 d][2048 s]
  const int b = bh >> 4, h = bh & 15;

  const int qA = p, qB = 31 - p;
  const int qgA = qA * 64 + wave * 16 + c;
  const int qgB = qB * 64 + wave * 16 + c;

  bf16x8 qfA[2], qfB[2];
#pragma unroll
  for (int dh = 0; dh < 2; dh++) {
    qfA[dh] = *(const bf16x8*)&Qb[(size_t)qgA * 64 + dh * 32 + quad * 8];
    qfB[dh] = *(const bf16x8*)&Qb[(size_t)qgB * 64 + dh * 32 + quad * 8];
  }

  bf16x8 ones;
#pragma unroll
  for (int j = 0; j < 8; j++) ones[j] = (bf16)1.0f;

  AttnState stA = {}, stB = {};

  const int ksr = lane >> 2, ksc = swz_stage_col(lane);
  const int krcol = swz_read_col(quad, c);
  const int vd = lane >> 3;                 // d-row within 8-row group
  const int vg = lane & 7;                  // LDS granule this lane fills

  // stage K tile (2 gld16) + V^T tile (2 gld16) for k-block kt into buf bb
  auto stage = [&](int bb, int kt) {
    const int kt64 = kt * 64;
#pragma unroll
    for (int i = 0; i < 2; i++) {
      const int seg = wave * 2 + i;
      const int dh = seg >> 2, r0 = (seg & 3) * 16;
      gld16(&Kb[(size_t)(kt64 + r0 + ksr) * 64 + dh * 32 + ksc],
            &Ks2[bb][dh][r0][0]);
    }
#pragma unroll
    for (int i = 0; i < 2; i++) {
      const int d0 = wave * 16 + i * 8;
      const int dd = d0 + vd;
      const int g = vg ^ (dd & 7);          // inverse-swizzled global granule
      gld16(&Vb[(size_t)dd * 2048 + kt64 + g * 8], &Vt[bb][d0][0]);
    }
  };

  auto load_kf = [&](int bb, bf16x8 (*kf)[2]) {
#pragma unroll
    for (int kg = 0; kg < 4; kg++)
#pragma unroll
      for (int dh = 0; dh < 2; dh++)
        kf[kg][dh] = *(const bf16x8*)&Ks2[bb][dh][kg * 16 + c][krcol];
  };
  auto load_vf = [&](int bb, bf16x8 (*vf)[2]) {
#pragma unroll
    for (int dg = 0; dg < 4; dg++) {
      const int d = dg * 16 + c;
#pragma unroll
      for (int ks = 0; ks < 2; ks++) {
        const int g = (ks * 4 + quad) ^ (c & 7);  // d&7 == c&7
        vf[dg][ks] = *(const bf16x8*)&Vt[bb][d][g * 8];
      }
    }
  };

  stage(0, 0);
  __syncthreads();

  int buf = 0;
  // region 1: both q-tiles active (kt = 0..qA), fused straight-line step
  for (int kt = 0; kt <= qA; kt++) {
    if (kt < qB) stage(buf ^ 1, kt + 1);  // async; loop-end barrier drains
    bf16x8 kf[4][2], vf[4][2];
    load_kf(buf, kf);
    load_vf(buf, vf);
    attn_step2(qfB, qfA, kf, vf, ones, Ps[wave][0], Ps[wave][1], stB, stA,
               qgA, kt * 64, kt == qA, c, quad);
    __syncthreads();
    buf ^= 1;
  }
  // region 2: B only (kt = qA+1..qB); diag for B at kt==qB
  for (int kt = qA + 1; kt <= qB; kt++) {
    if (kt < qB) stage(buf ^ 1, kt + 1);
    bf16x8 kf[4][2], vf[4][2];
    load_kf(buf, kf);
    load_vf(buf, vf);
    attn_step(qfB, kf, vf, ones, Ps[wave][0], stB, qgB, kt * 64, kt == qB, c,
              quad);
    __syncthreads();
    buf ^= 1;
  }

  const float ivA = 1.0f / stA.l[0], ivB = 1.0f / stB.l[0];

#pragma unroll
  for (int dg = 0; dg < 4; dg++) {
    const uint2 uA = {pack2(stA.o[dg][0] * ivA, stA.o[dg][1] * ivA),
                      pack2(stA.o[dg][2] * ivA, stA.o[dg][3] * ivA)};
    const uint2 uB = {pack2(stB.o[dg][0] * ivB, stB.o[dg][1] * ivB),
                      pack2(stB.o[dg][2] * ivB, stB.o[dg][3] * ivB)};
    *(uint2*)&Aout[((size_t)b * 2048 + qgA) * 1024 + h * 64 + dg * 16 + quad * 4] = uA;
    *(uint2*)&Aout[((size_t)b * 2048 + qgB) * 1024 + h * 64 + dg * 16 + quad * 4] = uB;
  }
}

// ---------------------------------------------------------------------------
extern "C" void kernel_launch(void* const* d_in, const int* in_sizes, int n_in,
                              void* d_out, int out_size, void* d_ws,
                              size_t ws_size, hipStream_t stream) {
  const float* x = (const float*)d_in[0];
  const float* W_qkv = (const float*)d_in[1];
  const float* b_qkv = (const float*)d_in[2];
  const float* W_out = (const float*)d_in[3];
  const float* b_out = (const float*)d_in[4];
  float* out = (float*)d_out;

  const int B = 2, S = 2048, NH = 16;
  const size_t qn = (size_t)B * NH * S * 64;

  bf16* xb = (bf16*)d_ws;
  bf16* Wqkvt = xb + qn;
  bf16* Wot = Wqkvt + 3072 * 1024;
  bf16* Qw = Wot + 1024 * 1024;
  bf16* Kw = Qw + qn;
  bf16* Vw = Kw + qn;   // stored transposed per head: V^T[bh][64 d][2048 s]
  bf16* AO = xb;  // alias: xb dead after gemm_qkv

  prep_kernel<<<dim3(4096), 256, 0, stream>>>(x, xb, W_qkv, Wqkvt, W_out, Wot);

  gemm_kernel<128, 1, 64><<<dim3(3072 / 128, 4096 / 128), 256, 0, stream>>>(
      xb, Wqkvt, b_qkv, Qw, Kw, Vw, 4096, 3072, 1024);
  attn_kernel<<<dim3(16, B * NH), 256, 0, stream>>>(Qw, Kw, Vw, AO);
  gemm_kernel<64, 0, 128><<<dim3(1024 / 64, 4096 / 128), 256, 0, stream>>>(
      AO, Wot, b_out, out, nullptr, nullptr, 4096, 1024, 1024);
}